// Round 12
// baseline (185.463 us; speedup 1.0000x reference)
//
#include <hip/hip_runtime.h>
#include <hip/hip_bf16.h>

#define HID    128     // hidden width per half
#define K256   256
#define TILE_M 32      // rows per block
#define TILE_E 64

typedef __attribute__((ext_vector_type(8))) short bf16x8;
typedef __attribute__((ext_vector_type(4))) float floatx4;

__device__ __forceinline__ unsigned short f2bf(float f) {
  __hip_bfloat16 b = __float2bfloat16(f);
  return __builtin_bit_cast(unsigned short, b);
}
__device__ __forceinline__ float bf2f(short s) {
  union { unsigned u; float f; } v; v.u = ((unsigned)(unsigned short)s) << 16;
  return v.f;
}
__device__ __forceinline__ bf16x8 pack8(float4 a, float4 b) {
  bf16x8 r;
  r[0] = (short)f2bf(a.x); r[1] = (short)f2bf(a.y);
  r[2] = (short)f2bf(a.z); r[3] = (short)f2bf(a.w);
  r[4] = (short)f2bf(b.x); r[5] = (short)f2bf(b.y);
  r[6] = (short)f2bf(b.z); r[7] = (short)f2bf(b.w);
  return r;
}
__device__ __forceinline__ float i8at(uint2 q, int j) {
  unsigned w = (j < 4) ? q.x : q.y;
  return (float)((int)(signed char)(w >> (8 * (j & 3))));
}

// ---------------- W1 prep: fp32 [128][256] -> fragment-ordered bf16 ----------------
__global__ __launch_bounds__(256)
void w1_prep(const float* __restrict__ W1, bf16x8* __restrict__ Wf)
{
  const int g    = blockIdx.x * 256 + threadIdx.x;   // 0..4095
  const int lane = g & 63;
  const int f    = g >> 6;                           // 0..63
  const int kt   = f & 3;
  const int nt   = (f >> 2) & 1;
  const int w    = (f >> 3) & 3;
  const int which= f >> 5;
  const int nlo  = lane & 15;
  const int quad = lane >> 4;
  const int n = w * 32 + nt * 16 + nlo;
  const int k = which * HID + kt * 32 + quad * 8;
  const float* p = W1 + (size_t)n * K256 + k;
  Wf[g] = pack8(*(const float4*)p, *(const float4*)(p + 4));
}

// ---------------- Phase 1: H = z * W1halfT  (M x 128, K=128) ----------------
// R6 PMC showed VALUBusy ~= Occupancy: waves are VALU-saturated at residency,
// so the fix must cut VALU AND raise residency together (R11 did only one).
// Reg-staged A (one load batch, cvt once per element in-reg, ds_write bf16),
// LDS = 8KB A16 + 8KB C (separate -> no A/C WAR barrier) = 16KB -> 8 blocks/CU
// (wave-cap). 2 barriers total. Signed int8 H storage.
__global__ __launch_bounds__(256, 8)
void node_proj(const float* __restrict__ zs, const float* __restrict__ zd,
               const bf16x8* __restrict__ Wf,
               unsigned char* __restrict__ Hqs, unsigned char* __restrict__ Hqd,
               float* __restrict__ Ss, float* __restrict__ Sd,
               int M)
{
  __shared__ unsigned short A16[TILE_M * HID];  // 8 KiB bf16 A-tile
  __shared__ unsigned short Cb[TILE_M * HID];   // 8 KiB bf16 C-tile

  const int which = blockIdx.y;
  const float* __restrict__ z = which ? zd : zs;
  unsigned char* __restrict__ Hq = which ? Hqd : Hqs;
  float* __restrict__ S = which ? Sd : Ss;

  const int tid  = threadIdx.x;
  const int lane = tid & 63;
  const int w    = tid >> 6;
  const int nlo  = lane & 15;
  const int quad = lane >> 4;
  const int r0   = blockIdx.x * TILE_M;

  // ---- issue A staging loads first (one batch: 2 x 32B per thread) ----
  float4 fa[2][2];
#pragma unroll
  for (int i = 0; i < 2; ++i) {
    const int j   = tid + i * 256;     // 32B-pair index, 0..511
    const int row = j >> 4;
    const int cp  = j & 15;            // 32B unit within row
    const int gr  = r0 + row;
    if (gr < M) {
      const float* p = z + (size_t)gr * HID + cp * 8;
      fa[i][0] = *(const float4*)p;
      fa[i][1] = *(const float4*)(p + 4);
    } else {
      fa[i][0] = (float4){0.f, 0.f, 0.f, 0.f};
      fa[i][1] = (float4){0.f, 0.f, 0.f, 0.f};
    }
  }

  // ---- W1 B-fragments: coalesced 16 B/lane from Wf (overlap z-load latency) ----
  bf16x8 bfr[2][4];
  const int nb = w * 32;
  {
    const bf16x8* fw = Wf + ((size_t)(which * 4 + w) * 2) * 4 * 64;
#pragma unroll
    for (int nt = 0; nt < 2; ++nt)
#pragma unroll
      for (int kt = 0; kt < 4; ++kt)
        bfr[nt][kt] = fw[(nt * 4 + kt) * 64 + lane];
  }

  // ---- cvt once per element, ds_write bf16 (XOR-chunk swizzle) ----
#pragma unroll
  for (int i = 0; i < 2; ++i) {
    const int j   = tid + i * 256;
    const int row = j >> 4;
    const int cp  = j & 15;
    *(bf16x8*)(A16 + row * HID + ((cp ^ (row & 15)) * 8)) = pack8(fa[i][0], fa[i][1]);
  }
  __syncthreads();

  // ---- MFMA: bf16 fragments, 1 ds_read_b128 each ----
  floatx4 acc[2][2];
#pragma unroll
  for (int mt = 0; mt < 2; ++mt)
#pragma unroll
    for (int nt = 0; nt < 2; ++nt)
      acc[mt][nt] = (floatx4){0.f, 0.f, 0.f, 0.f};

#pragma unroll
  for (int kt = 0; kt < 4; ++kt) {
    bf16x8 a[2];
#pragma unroll
    for (int mt = 0; mt < 2; ++mt) {
      const int m  = mt * 16 + nlo;
      const int cb = (kt * 4 + quad) ^ nlo;          // row&15 == nlo
      a[mt] = *(const bf16x8*)(A16 + m * HID + cb * 8);
    }
#pragma unroll
    for (int mt = 0; mt < 2; ++mt)
#pragma unroll
      for (int nt = 0; nt < 2; ++nt)
        acc[mt][nt] = __builtin_amdgcn_mfma_f32_16x16x32_bf16(
            a[mt], bfr[nt][kt], acc[mt][nt], 0, 0, 0);
  }

  // ---- C -> Cb (separate buffer: no WAR barrier against A16 reads) ----
#pragma unroll
  for (int mt = 0; mt < 2; ++mt) {
#pragma unroll
    for (int r = 0; r < 4; ++r) {
      const int rowl = mt * 16 + quad * 4 + r;
#pragma unroll
      for (int nt = 0; nt < 2; ++nt) {
        const int col = nb + nt * 16 + nlo;
        const int sw  = ((col >> 3) ^ (rowl & 15)) * 8 + (col & 7);
        Cb[rowl * HID + sw] = f2bf(acc[mt][nt][r]);
      }
    }
  }
  __syncthreads();

  // ---- signed-int8 quantized store: per-row amax scale, 8 B/thread ----
#pragma unroll
  for (int i = 0; i < 2; ++i) {
    const int c   = tid + i * 256;
    const int row = c >> 4;
    const int c16 = c & 15;
    const int gr  = r0 + row;
    bf16x8 v = *(const bf16x8*)(Cb + row * HID + ((c16 ^ (row & 15)) * 8));
    float x[8];
    float m = 0.f;
#pragma unroll
    for (int j = 0; j < 8; ++j) {
      x[j] = bf2f(v[j]);
      m = fmaxf(m, __builtin_fabsf(x[j]));
    }
    m = fmaxf(m, __shfl_xor(m, 1));
    m = fmaxf(m, __shfl_xor(m, 2));
    m = fmaxf(m, __shfl_xor(m, 4));
    m = fmaxf(m, __shfl_xor(m, 8));
    const float inv = (m > 0.f) ? 127.f / m : 0.f;
    unsigned lo = 0, hi = 0;
#pragma unroll
    for (int j = 0; j < 4; ++j) {
      const int q = (int)rintf(x[j] * inv);
      lo |= ((unsigned)(q & 0xff)) << (8 * j);
    }
#pragma unroll
    for (int j = 0; j < 4; ++j) {
      const int q = (int)rintf(x[4 + j] * inv);
      hi |= ((unsigned)(q & 0xff)) << (8 * j);
    }
    if (gr < M) {
      *(uint2*)(Hq + (size_t)gr * HID + c16 * 8) = make_uint2(lo, hi);
      if (c16 == 0) S[gr] = m * (1.f / 127.f);
    }
  }
}

// ---------------- Phase 2: out[e] = W2 . relu(dq(Hqs[row]) + dq(Hqd[col]) + b1) + b2 ----
// FROZEN at measured best (44.9-46.1 us across 6 variants; gather-service-bound).
__global__ __launch_bounds__(256, 8)
void edge_eval(const unsigned char* __restrict__ Hqs,
               const unsigned char* __restrict__ Hqd,
               const float* __restrict__ Ss, const float* __restrict__ Sd,
               const int* __restrict__ eidx,
               const float* __restrict__ b1, const float* __restrict__ W2,
               const float* __restrict__ b2,
               float* __restrict__ out, int E)
{
  const int tid = threadIdx.x;
  const int l16 = tid & 15;
  const int ebase = blockIdx.x * 64 + (tid >> 4) * 4;

  int rows[4], cols[4];
#pragma unroll
  for (int u = 0; u < 4; ++u) {
    const int e = ebase + u;
    const bool ok = e < E;
    rows[u] = ok ? eidx[e] : 0;
    cols[u] = ok ? eidx[E + e] : 0;
  }

  uint2 qs[4], qd[4];
  float ss[4], sd[4];
#pragma unroll
  for (int u = 0; u < 4; ++u)
    qs[u] = *(const uint2*)(Hqs + (size_t)rows[u] * HID + l16 * 8);
#pragma unroll
  for (int u = 0; u < 4; ++u)
    qd[u] = *(const uint2*)(Hqd + (size_t)cols[u] * HID + l16 * 8);
#pragma unroll
  for (int u = 0; u < 4; ++u) ss[u] = Ss[rows[u]];
#pragma unroll
  for (int u = 0; u < 4; ++u) sd[u] = Sd[cols[u]];

  float4 b1a = *(const float4*)(b1 + l16 * 8);
  float4 b1b = *(const float4*)(b1 + l16 * 8 + 4);
  float4 w2a = *(const float4*)(W2 + l16 * 8);
  float4 w2b = *(const float4*)(W2 + l16 * 8 + 4);
  const float b1v[8] = {b1a.x, b1a.y, b1a.z, b1a.w, b1b.x, b1b.y, b1b.z, b1b.w};
  const float w2v[8] = {w2a.x, w2a.y, w2a.z, w2a.w, w2b.x, w2b.y, w2b.z, w2b.w};
  const float bias2 = b2[0];

  float v[4];
#pragma unroll
  for (int u = 0; u < 4; ++u) {
    float s = 0.f;
#pragma unroll
    for (int j = 0; j < 8; ++j) {
      float x = fmaf(i8at(qs[u], j), ss[u], fmaf(i8at(qd[u], j), sd[u], b1v[j]));
      x = fmaxf(x, 0.f);
      s = fmaf(x, w2v[j], s);
    }
    s += __shfl_xor(s, 1);
    s += __shfl_xor(s, 2);
    s += __shfl_xor(s, 4);
    s += __shfl_xor(s, 8);
    v[u] = s;
  }
  if (l16 < 4) {
    const int e = ebase + l16;
    const float vo = (l16 == 0) ? v[0] : (l16 == 1) ? v[1] : (l16 == 2) ? v[2] : v[3];
    if (e < E) out[e] = vo + bias2;
  }
}

// ---------------- Fallback (ws too small): fused kernel, fp32 direct ----------------
__global__ __launch_bounds__(256, 4)
void edge_decoder_f32(const float* __restrict__ zsrc_f, const float* __restrict__ zdst_f,
                      const int* __restrict__ eidx,
                      const float* __restrict__ W1f,
                      const float* __restrict__ b1, const float* __restrict__ W2,
                      const float* __restrict__ b2,
                      float* __restrict__ out, int E)
{
  __shared__ unsigned short Zt[TILE_E * K256];
  __shared__ int   idxs[2 * TILE_E];
  __shared__ float part[4 * TILE_E];

  const int tid  = threadIdx.x;
  const int lane = tid & 63;
  const int nh   = tid >> 6;
  const int nlo  = lane & 15;
  const int quad = lane >> 4;
  const int e0   = blockIdx.x * TILE_E;

  if (tid < 2 * TILE_E) {
    const int ee = e0 + (tid & 63);
    idxs[tid] = (ee < E) ? eidx[(tid >> 6) * E + ee] : 0;
  }
  __syncthreads();

#pragma unroll
  for (int it = 0; it < 8; ++it) {
    const int c   = tid + it * 256;
    const int row = c >> 4;
    const int l16 = c & 15;
    const int e   = row >> 1;
    const int h   = row & 1;
    const int node = idxs[h * TILE_E + e];
    const int cs  = ((h << 4) | l16) ^ (e & 31);
    const float* p = (h ? zdst_f : zsrc_f) + (size_t)node * HID + l16 * 8;
    bf16x8 v = pack8(*(const float4*)p, *(const float4*)(p + 4));
    *(bf16x8*)(Zt + e * K256 + cs * 8) = v;
  }
  __syncthreads();

  bf16x8 w1f[2][8];
  const int nb = nh * 32;
#pragma unroll
  for (int nt = 0; nt < 2; ++nt) {
    const int n = nb + nt * 16 + nlo;
#pragma unroll
    for (int kt = 0; kt < 8; ++kt) {
      const float* p = W1f + (size_t)n * K256 + kt * 32 + quad * 8;
      w1f[nt][kt] = pack8(*(const float4*)p, *(const float4*)(p + 4));
    }
  }

  floatx4 acc[4][2];
#pragma unroll
  for (int mt = 0; mt < 4; ++mt)
#pragma unroll
    for (int nt = 0; nt < 2; ++nt)
      acc[mt][nt] = (floatx4){0.f, 0.f, 0.f, 0.f};

#pragma unroll
  for (int kt = 0; kt < 8; ++kt) {
    bf16x8 a[4];
#pragma unroll
    for (int mt = 0; mt < 4; ++mt) {
      const int m  = mt * 16 + nlo;
      const int cs = (kt * 4 + quad) ^ (m & 31);
      a[mt] = *(const bf16x8*)(Zt + m * K256 + cs * 8);
    }
#pragma unroll
    for (int mt = 0; mt < 4; ++mt)
#pragma unroll
      for (int nt = 0; nt < 2; ++nt)
        acc[mt][nt] = __builtin_amdgcn_mfma_f32_16x16x32_bf16(
            a[mt], w1f[nt][kt], acc[mt][nt], 0, 0, 0);
  }

  float b1v[2], w2v[2];
#pragma unroll
  for (int nt = 0; nt < 2; ++nt) {
    const int n = nb + nt * 16 + nlo;
    b1v[nt] = b1[n];
    w2v[nt] = W2[n];
  }
#pragma unroll
  for (int mt = 0; mt < 4; ++mt) {
#pragma unroll
    for (int r = 0; r < 4; ++r) {
      float v = 0.f;
#pragma unroll
      for (int nt = 0; nt < 2; ++nt) {
        float x = acc[mt][nt][r] + b1v[nt];
        x = fmaxf(x, 0.f);
        v = fmaf(x, w2v[nt], v);
      }
      v += __shfl_xor(v, 1);
      v += __shfl_xor(v, 2);
      v += __shfl_xor(v, 4);
      v += __shfl_xor(v, 8);
      if (nlo == 0)
        part[nh * TILE_E + mt * 16 + quad * 4 + r] = v;
    }
  }
  __syncthreads();
  if (tid < TILE_E && e0 + tid < E)
    out[e0 + tid] = part[tid] + part[TILE_E + tid] + part[2 * TILE_E + tid]
                  + part[3 * TILE_E + tid] + b2[0];
}

extern "C" void kernel_launch(void* const* d_in, const int* in_sizes, int n_in,
                              void* d_out, int out_size, void* d_ws, size_t ws_size,
                              hipStream_t stream) {
  const float* z_src = (const float*)d_in[0];
  const float* z_dst = (const float*)d_in[1];
  const int*   eidx  = (const int*)d_in[2];
  const float* W1    = (const float*)d_in[3];
  const float* b1    = (const float*)d_in[4];
  const float* W2    = (const float*)d_in[5];
  const float* b2    = (const float*)d_in[6];
  float* out = (float*)d_out;

  const int NH = in_sizes[0];        // 12,800,000 = M * 128
  const int M  = NH / HID;           // 100,000
  const int E  = in_sizes[2] / 2;    // 1,000,000

  const size_t rowBytes = (size_t)M * HID;                    // int8 per side
  const size_t wfBytes  = 64 * 64 * 16;                       // 64 frags x 64 lanes x 16 B
  const size_t need = rowBytes * 2 + 2 * (size_t)M * sizeof(float) + wfBytes;
  if (ws_size >= need) {
    unsigned char* Hqs = (unsigned char*)d_ws;
    unsigned char* Hqd = Hqs + rowBytes;
    float* Ss = (float*)(Hqd + rowBytes);
    float* Sd = Ss + M;
    bf16x8* Wf = (bf16x8*)(Sd + M);
    const int nMt = (M + TILE_M - 1) / TILE_M;   // 3125
    w1_prep<<<16, 256, 0, stream>>>(W1, Wf);
    node_proj<<<dim3(nMt, 2), 256, 0, stream>>>(z_src, z_dst, Wf, Hqs, Hqd, Ss, Sd, M);
    edge_eval<<<(E + 63) / 64, 256, 0, stream>>>(Hqs, Hqd, Ss, Sd, eidx, b1, W2, b2, out, E);
  } else {
    const int nblk = (E + TILE_E - 1) / TILE_E;
    edge_decoder_f32<<<nblk, 256, 0, stream>>>(z_src, z_dst, eidx, W1, b1, W2, b2, out, E);
  }
}

// Round 13
// 182.104 us; speedup vs baseline: 1.0184x; 1.0184x over previous
//
#include <hip/hip_runtime.h>
#include <hip/hip_bf16.h>

#define HID    128     // hidden width per half
#define K256   256
#define TILE_M 64      // rows per block
#define TILE_E 64

typedef __attribute__((ext_vector_type(8))) short bf16x8;
typedef __attribute__((ext_vector_type(4))) float floatx4;

__device__ __forceinline__ unsigned short f2bf(float f) {
  __hip_bfloat16 b = __float2bfloat16(f);
  return __builtin_bit_cast(unsigned short, b);
}
__device__ __forceinline__ float bf2f(short s) {
  union { unsigned u; float f; } v; v.u = ((unsigned)(unsigned short)s) << 16;
  return v.f;
}
__device__ __forceinline__ bf16x8 pack8(float4 a, float4 b) {
  bf16x8 r;
  r[0] = (short)f2bf(a.x); r[1] = (short)f2bf(a.y);
  r[2] = (short)f2bf(a.z); r[3] = (short)f2bf(a.w);
  r[4] = (short)f2bf(b.x); r[5] = (short)f2bf(b.y);
  r[6] = (short)f2bf(b.z); r[7] = (short)f2bf(b.w);
  return r;
}
__device__ __forceinline__ float i8at(uint2 q, int j) {
  unsigned w = (j < 4) ? q.x : q.y;
  return (float)((int)(signed char)(w >> (8 * (j & 3))));
}

// async 16B global->LDS DMA (lds dest: wave-uniform base + lane*16)
__device__ __forceinline__ void gload_lds16(const float* g, void* l) {
  __builtin_amdgcn_global_load_lds(
      (const __attribute__((address_space(1))) unsigned int*)g,
      (__attribute__((address_space(3))) unsigned int*)l, 16, 0, 0);
}

// ---------------- W1 prep: fp32 [128][256] -> fragment-ordered bf16 ----------------
// Wf[f][lane] with f = ((which*4 + w)*2 + nt)*4 + kt; 64 frags x 64 lanes x 16 B.
// Turns node_proj's 64-distinct-line-per-inst W1 gathers into coalesced loads.
__global__ __launch_bounds__(256)
void w1_prep(const float* __restrict__ W1, bf16x8* __restrict__ Wf)
{
  const int g    = blockIdx.x * 256 + threadIdx.x;   // 0..4095
  const int lane = g & 63;
  const int f    = g >> 6;                           // 0..63
  const int kt   = f & 3;
  const int nt   = (f >> 2) & 1;
  const int w    = (f >> 3) & 3;
  const int which= f >> 5;
  const int nlo  = lane & 15;
  const int quad = lane >> 4;
  const int n = w * 32 + nt * 16 + nlo;
  const int k = which * HID + kt * 32 + quad * 8;
  const float* p = W1 + (size_t)n * K256 + k;
  Wf[g] = pack8(*(const float4*)p, *(const float4*)(p + 4));
}

// ---------------- Phase 1: H = z * W1halfT  (M x 128, K=128) ----------------
// A-tile staged fp32 via global_load_lds DMA (pre-swizzled source, T21).
// W1 B-fragments read COALESCED from the pre-fragmented Wf table.
__global__ __launch_bounds__(256, 4)
void node_proj(const float* __restrict__ zs, const float* __restrict__ zd,
               const bf16x8* __restrict__ Wf,
               unsigned char* __restrict__ Hqs, unsigned char* __restrict__ Hqd,
               float* __restrict__ Ss, float* __restrict__ Sd,
               int M)
{
  __shared__ float Af[TILE_M * HID];           // 32 KiB fp32 A-tile; reused as bf16 C-tile
  unsigned short* At = (unsigned short*)Af;    // alias for epilogue

  const int which = blockIdx.y;
  const float* __restrict__ z = which ? zd : zs;
  unsigned char* __restrict__ Hq = which ? Hqd : Hqs;
  float* __restrict__ S = which ? Sd : Ss;

  const int tid  = threadIdx.x;
  const int lane = tid & 63;
  const int w    = tid >> 6;
  const int nlo  = lane & 15;
  const int quad = lane >> 4;
  const int r0   = blockIdx.x * TILE_M;

  // ---- issue A-tile DMA first (8 x 16B per thread, back-to-back) ----
#pragma unroll
  for (int i = 0; i < 8; ++i) {
    const int off = w * 8192 + i * 1024 + lane * 16;   // byte offset in tile
    const int row = off >> 9;                          // /512 B per row
    const int p   = (off >> 4) & 31;                   // 16B chunk within row
    const int c   = p ^ (row & 15);
    int gr = r0 + row;
    gr = (gr < M) ? gr : (M - 1);                      // clamp; masked at store
    gload_lds16(z + (size_t)gr * HID + c * 4,
                (char*)Af + w * 8192 + i * 1024);
  }

  // ---- W1 B-fragments: coalesced 16 B/lane from Wf (overlaps DMA latency) ----
  bf16x8 bfr[2][4];
  const int nb = w * 32;
  {
    const bf16x8* fw = Wf + ((size_t)(which * 4 + w) * 2) * 4 * 64;
#pragma unroll
    for (int nt = 0; nt < 2; ++nt)
#pragma unroll
      for (int kt = 0; kt < 4; ++kt)
        bfr[nt][kt] = fw[(nt * 4 + kt) * 64 + lane];
  }
  __syncthreads();   // drains vmcnt (DMA) + lgkm

  // ---- MFMA: fragments read fp32 (2 x ds_read_b128, XOR-deswizzled) + cvt ----
  floatx4 acc[4][2];
#pragma unroll
  for (int mt = 0; mt < 4; ++mt)
#pragma unroll
    for (int nt = 0; nt < 2; ++nt)
      acc[mt][nt] = (floatx4){0.f, 0.f, 0.f, 0.f};

#pragma unroll
  for (int kt = 0; kt < 4; ++kt) {
    bf16x8 a[4];
#pragma unroll
    for (int mt = 0; mt < 4; ++mt) {
      const int m  = mt * 16 + nlo;
      const int c0 = kt * 8 + quad * 2;                // global 16B chunk (4 fp32)
      const int p0 = c0 ^ nlo;
      const int p1 = (c0 + 1) ^ nlo;
      float4 fa = *(const float4*)(Af + m * HID + p0 * 4);
      float4 fb = *(const float4*)(Af + m * HID + p1 * 4);
      a[mt] = pack8(fa, fb);
    }
#pragma unroll
    for (int mt = 0; mt < 4; ++mt)
#pragma unroll
      for (int nt = 0; nt < 2; ++nt)
        acc[mt][nt] = __builtin_amdgcn_mfma_f32_16x16x32_bf16(
            a[mt], bfr[nt][kt], acc[mt][nt], 0, 0, 0);
  }

  __syncthreads();                          // all A reads done -> reuse LDS for C
  // ---- C -> LDS (bf16, XOR-chunk swizzle) ----
#pragma unroll
  for (int mt = 0; mt < 4; ++mt) {
#pragma unroll
    for (int r = 0; r < 4; ++r) {
      const int rowl = mt * 16 + quad * 4 + r;
#pragma unroll
      for (int nt = 0; nt < 2; ++nt) {
        const int col = nb + nt * 16 + nlo;
        const int sw  = ((col >> 3) ^ (rowl & 15)) * 8 + (col & 7);
        At[rowl * HID + sw] = f2bf(acc[mt][nt][r]);
      }
    }
  }
  __syncthreads();

  // ---- int8 quantized store: per-row amax scale, 8 B/thread ----
#pragma unroll
  for (int i = 0; i < 4; ++i) {
    const int c   = tid + i * 256;
    const int row = c >> 4;
    const int c16 = c & 15;
    const int gr  = r0 + row;
    bf16x8 v = *(const bf16x8*)(At + row * HID + ((c16 ^ (row & 15)) * 8));
    float x[8];
    float m = 0.f;
#pragma unroll
    for (int j = 0; j < 8; ++j) {
      x[j] = bf2f(v[j]);
      m = fmaxf(m, __builtin_fabsf(x[j]));
    }
    m = fmaxf(m, __shfl_xor(m, 1));
    m = fmaxf(m, __shfl_xor(m, 2));
    m = fmaxf(m, __shfl_xor(m, 4));
    m = fmaxf(m, __shfl_xor(m, 8));
    const float inv = (m > 0.f) ? 127.f / m : 0.f;
    unsigned lo = 0, hi = 0;
#pragma unroll
    for (int j = 0; j < 4; ++j) {
      const int q = (int)rintf(x[j] * inv);
      lo |= ((unsigned)(q & 0xff)) << (8 * j);
    }
#pragma unroll
    for (int j = 0; j < 4; ++j) {
      const int q = (int)rintf(x[4 + j] * inv);
      hi |= ((unsigned)(q & 0xff)) << (8 * j);
    }
    if (gr < M) {
      *(uint2*)(Hq + (size_t)gr * HID + c16 * 8) = make_uint2(lo, hi);
      if (c16 == 0) S[gr] = m * (1.f / 127.f);
    }
  }
}

// ---------------- Phase 2: out[e] = W2 . relu(dq(Hqs[row]) + dq(Hqd[col]) + b1) + b2 ----
// FROZEN at measured best (44.9-48.4 us across runs; gather-service-bound at
// ~88% of achievable demand-side BW: 2M random 128-B gathers / 46 us = 5.6 TB/s).
__global__ __launch_bounds__(256, 8)
void edge_eval(const unsigned char* __restrict__ Hqs,
               const unsigned char* __restrict__ Hqd,
               const float* __restrict__ Ss, const float* __restrict__ Sd,
               const int* __restrict__ eidx,
               const float* __restrict__ b1, const float* __restrict__ W2,
               const float* __restrict__ b2,
               float* __restrict__ out, int E)
{
  const int tid = threadIdx.x;
  const int l16 = tid & 15;
  const int ebase = blockIdx.x * 64 + (tid >> 4) * 4;

  int rows[4], cols[4];
#pragma unroll
  for (int u = 0; u < 4; ++u) {
    const int e = ebase + u;
    const bool ok = e < E;
    rows[u] = ok ? eidx[e] : 0;
    cols[u] = ok ? eidx[E + e] : 0;
  }

  uint2 qs[4], qd[4];
  float ss[4], sd[4];
#pragma unroll
  for (int u = 0; u < 4; ++u)
    qs[u] = *(const uint2*)(Hqs + (size_t)rows[u] * HID + l16 * 8);
#pragma unroll
  for (int u = 0; u < 4; ++u)
    qd[u] = *(const uint2*)(Hqd + (size_t)cols[u] * HID + l16 * 8);
#pragma unroll
  for (int u = 0; u < 4; ++u) ss[u] = Ss[rows[u]];
#pragma unroll
  for (int u = 0; u < 4; ++u) sd[u] = Sd[cols[u]];

  float4 b1a = *(const float4*)(b1 + l16 * 8);
  float4 b1b = *(const float4*)(b1 + l16 * 8 + 4);
  float4 w2a = *(const float4*)(W2 + l16 * 8);
  float4 w2b = *(const float4*)(W2 + l16 * 8 + 4);
  const float b1v[8] = {b1a.x, b1a.y, b1a.z, b1a.w, b1b.x, b1b.y, b1b.z, b1b.w};
  const float w2v[8] = {w2a.x, w2a.y, w2a.z, w2a.w, w2b.x, w2b.y, w2b.z, w2b.w};
  const float bias2 = b2[0];

  float v[4];
#pragma unroll
  for (int u = 0; u < 4; ++u) {
    float s = 0.f;
#pragma unroll
    for (int j = 0; j < 8; ++j) {
      float x = fmaf(i8at(qs[u], j), ss[u], fmaf(i8at(qd[u], j), sd[u], b1v[j]));
      x = fmaxf(x, 0.f);
      s = fmaf(x, w2v[j], s);
    }
    s += __shfl_xor(s, 1);
    s += __shfl_xor(s, 2);
    s += __shfl_xor(s, 4);
    s += __shfl_xor(s, 8);
    v[u] = s;
  }
  if (l16 < 4) {
    const int e = ebase + l16;
    const float vo = (l16 == 0) ? v[0] : (l16 == 1) ? v[1] : (l16 == 2) ? v[2] : v[3];
    if (e < E) out[e] = vo + bias2;
  }
}

// ---------------- Fallback (ws too small): fused kernel, fp32 direct ----------------
__global__ __launch_bounds__(256, 4)
void edge_decoder_f32(const float* __restrict__ zsrc_f, const float* __restrict__ zdst_f,
                      const int* __restrict__ eidx,
                      const float* __restrict__ W1f,
                      const float* __restrict__ b1, const float* __restrict__ W2,
                      const float* __restrict__ b2,
                      float* __restrict__ out, int E)
{
  __shared__ unsigned short Zt[TILE_E * K256];
  __shared__ int   idxs[2 * TILE_E];
  __shared__ float part[4 * TILE_E];

  const int tid  = threadIdx.x;
  const int lane = tid & 63;
  const int nh   = tid >> 6;
  const int nlo  = lane & 15;
  const int quad = lane >> 4;
  const int e0   = blockIdx.x * TILE_E;

  if (tid < 2 * TILE_E) {
    const int ee = e0 + (tid & 63);
    idxs[tid] = (ee < E) ? eidx[(tid >> 6) * E + ee] : 0;
  }
  __syncthreads();

#pragma unroll
  for (int it = 0; it < 8; ++it) {
    const int c   = tid + it * 256;
    const int row = c >> 4;
    const int l16 = c & 15;
    const int e   = row >> 1;
    const int h   = row & 1;
    const int node = idxs[h * TILE_E + e];
    const int cs  = ((h << 4) | l16) ^ (e & 31);
    const float* p = (h ? zdst_f : zsrc_f) + (size_t)node * HID + l16 * 8;
    bf16x8 v = pack8(*(const float4*)p, *(const float4*)(p + 4));
    *(bf16x8*)(Zt + e * K256 + cs * 8) = v;
  }
  __syncthreads();

  bf16x8 w1f[2][8];
  const int nb = nh * 32;
#pragma unroll
  for (int nt = 0; nt < 2; ++nt) {
    const int n = nb + nt * 16 + nlo;
#pragma unroll
    for (int kt = 0; kt < 8; ++kt) {
      const float* p = W1f + (size_t)n * K256 + kt * 32 + quad * 8;
      w1f[nt][kt] = pack8(*(const float4*)p, *(const float4*)(p + 4));
    }
  }

  floatx4 acc[4][2];
#pragma unroll
  for (int mt = 0; mt < 4; ++mt)
#pragma unroll
    for (int nt = 0; nt < 2; ++nt)
      acc[mt][nt] = (floatx4){0.f, 0.f, 0.f, 0.f};

#pragma unroll
  for (int kt = 0; kt < 8; ++kt) {
    bf16x8 a[4];
#pragma unroll
    for (int mt = 0; mt < 4; ++mt) {
      const int m  = mt * 16 + nlo;
      const int cs = (kt * 4 + quad) ^ (m & 31);
      a[mt] = *(const bf16x8*)(Zt + m * K256 + cs * 8);
    }
#pragma unroll
    for (int mt = 0; mt < 4; ++mt)
#pragma unroll
      for (int nt = 0; nt < 2; ++nt)
        acc[mt][nt] = __builtin_amdgcn_mfma_f32_16x16x32_bf16(
            a[mt], w1f[nt][kt], acc[mt][nt], 0, 0, 0);
  }

  float b1v[2], w2v[2];
#pragma unroll
  for (int nt = 0; nt < 2; ++nt) {
    const int n = nb + nt * 16 + nlo;
    b1v[nt] = b1[n];
    w2v[nt] = W2[n];
  }
#pragma unroll
  for (int mt = 0; mt < 4; ++mt) {
#pragma unroll
    for (int r = 0; r < 4; ++r) {
      float v = 0.f;
#pragma unroll
      for (int nt = 0; nt < 2; ++nt) {
        float x = acc[mt][nt][r] + b1v[nt];
        x = fmaxf(x, 0.f);
        v = fmaf(x, w2v[nt], v);
      }
      v += __shfl_xor(v, 1);
      v += __shfl_xor(v, 2);
      v += __shfl_xor(v, 4);
      v += __shfl_xor(v, 8);
      if (nlo == 0)
        part[nh * TILE_E + mt * 16 + quad * 4 + r] = v;
    }
  }
  __syncthreads();
  if (tid < TILE_E && e0 + tid < E)
    out[e0 + tid] = part[tid] + part[TILE_E + tid] + part[2 * TILE_E + tid]
                  + part[3 * TILE_E + tid] + b2[0];
}

extern "C" void kernel_launch(void* const* d_in, const int* in_sizes, int n_in,
                              void* d_out, int out_size, void* d_ws, size_t ws_size,
                              hipStream_t stream) {
  const float* z_src = (const float*)d_in[0];
  const float* z_dst = (const float*)d_in[1];
  const int*   eidx  = (const int*)d_in[2];
  const float* W1    = (const float*)d_in[3];
  const float* b1    = (const float*)d_in[4];
  const float* W2    = (const float*)d_in[5];
  const float* b2    = (const float*)d_in[6];
  float* out = (float*)d_out;

  const int NH = in_sizes[0];        // 12,800,000 = M * 128
  const int M  = NH / HID;           // 100,000
  const int E  = in_sizes[2] / 2;    // 1,000,000

  const size_t rowBytes = (size_t)M * HID;                    // int8 per side
  const size_t wfBytes  = 64 * 64 * 16;                       // 64 frags x 64 lanes x 16 B
  const size_t need = rowBytes * 2 + 2 * (size_t)M * sizeof(float) + wfBytes;
  if (ws_size >= need) {
    unsigned char* Hqs = (unsigned char*)d_ws;
    unsigned char* Hqd = Hqs + rowBytes;
    float* Ss = (float*)(Hqd + rowBytes);
    float* Sd = Ss + M;
    bf16x8* Wf = (bf16x8*)(Sd + M);
    const int nMt = (M + TILE_M - 1) / TILE_M;   // 1563
    w1_prep<<<16, 256, 0, stream>>>(W1, Wf);
    node_proj<<<dim3(nMt, 2), 256, 0, stream>>>(z_src, z_dst, Wf, Hqs, Hqd, Ss, Sd, M);
    edge_eval<<<(E + 63) / 64, 256, 0, stream>>>(Hqs, Hqd, Ss, Sd, eidx, b1, W2, b2, out, E);
  } else {
    const int nblk = (E + TILE_E - 1) / TILE_E;
    edge_decoder_f32<<<nblk, 256, 0, stream>>>(z_src, z_dst, eidx, W1, b1, W2, b2, out, E);
  }
}